// Round 3
// baseline (306.608 us; speedup 1.0000x reference)
//
#include <hip/hip_runtime.h>
#include <hip/hip_bf16.h>

#define D   128   // EMBED_DIM
#define D2  256   // 2*EMBED_DIM
#define H1P 272   // padded h1 tile row (ushorts)

typedef short bf16x8 __attribute__((ext_vector_type(8)));
typedef float f32x4  __attribute__((ext_vector_type(4)));

__device__ __forceinline__ float bf2f(unsigned short u) {
    return __uint_as_float(((unsigned int)u) << 16);
}
__device__ __forceinline__ float bflo(unsigned int p) { return __uint_as_float(p << 16); }
__device__ __forceinline__ float bfhi(unsigned int p) { return __uint_as_float(p & 0xffff0000u); }
__device__ __forceinline__ unsigned short f2bf(float f) {
    __hip_bfloat16 h = __float2bfloat16(f);
    return *(unsigned short*)&h;
}

template<bool BF>
__device__ __forceinline__ float ld1(const void* p, size_t i) {
    if constexpr (BF) return bf2f(((const unsigned short*)p)[i]);
    else              return ((const float*)p)[i];
}

template<bool BF>
__device__ __forceinline__ void load8f(const void* p, size_t elem_off, float* r) {
    if constexpr (BF) {
        uint4 v = *(const uint4*)((const unsigned short*)p + elem_off);
        r[0]=bflo(v.x); r[1]=bfhi(v.x); r[2]=bflo(v.y); r[3]=bfhi(v.y);
        r[4]=bflo(v.z); r[5]=bfhi(v.z); r[6]=bflo(v.w); r[7]=bfhi(v.w);
    } else {
        const float4* q = (const float4*)((const float*)p + elem_off);
        float4 a = q[0], b = q[1];
        r[0]=a.x; r[1]=a.y; r[2]=a.z; r[3]=a.w;
        r[4]=b.x; r[5]=b.y; r[6]=b.z; r[7]=b.w;
    }
}

__device__ __forceinline__ void unpack8(uint4 v, float* r) {
    r[0]=bflo(v.x); r[1]=bfhi(v.x); r[2]=bflo(v.y); r[3]=bfhi(v.y);
    r[4]=bflo(v.z); r[5]=bfhi(v.z); r[6]=bflo(v.w); r[7]=bfhi(v.w);
}

__device__ __forceinline__ void store8bf(unsigned short* p, const float* r) {
    union { unsigned short u[8]; uint4 v; } pk;
    #pragma unroll
    for (int k = 0; k < 8; ++k) pk.u[k] = f2bf(r[k]);
    *(uint4*)p = pk.v;
}

__device__ __forceinline__ bool read_mask(const void* mask, int mmode, size_t i) {
    if (mmode == 0) return ((const int*)mask)[i] != 0;
    if (mmode == 1) return ((const unsigned char*)mask)[i] != 0;
    return ((const unsigned short*)mask)[i] != 0;
}

// Wave-local dtype probe (no LDS, no barrier): identical count in every wave.
__device__ __forceinline__ bool probe_is_bf16(const unsigned int* probe) {
    const int lane = threadIdx.x & 63;
    int cnt = 0;
    #pragma unroll
    for (int i = 0; i < 4; ++i) {
        unsigned int e = (probe[lane + 64 * i] >> 7) & 0xffu;
        cnt += (e >= 90 && e < 130) ? 1 : 0;
    }
    #pragma unroll
    for (int o = 32; o; o >>= 1) cnt += __shfl_xor(cnt, o);
    return cnt >= 128;
}

// ---------------------------------------------------------------------------
// Kernel 1 (v2): load-balanced attention.  ONE BLOCK (4 waves) PER ROW.
// Wave w owns item-group w (items [32w, 32w+32)); inactive waves contribute
// zeros.  Partials (esum, acc[128]) combined through 2KB LDS + one barrier.
// Block durations are ~uniform (<= T(32 items)); 32 blocks/CU queued gives
// backfill, fixing the exact-fit-grid load-imbalance (Occupancy 32% at R1).
// ---------------------------------------------------------------------------
template<bool BF>
__device__ __forceinline__ void attn_row(
    const int* __restrict__ x_u, const int* __restrict__ x_b,
    const int* __restrict__ items, const void* __restrict__ mask, int mmode,
    const void* __restrict__ emb_u, const void* __restrict__ emb_i,
    const void* __restrict__ emb_b, const void* __restrict__ Aw,
    unsigned short* __restrict__ h_out, int L,
    float (*s_acc)[128], float* s_es)
{
    const int lane = threadIdx.x & 63;
    const int wv   = threadIdx.x >> 6;   // item-group index 0..3
    const int b    = blockIdx.x;

    const int xu = x_u[b];

    // ---- items + mask: lane holds item[lane] (i0), item[64+lane] (i1) ----
    const int  c0 = (lane < L) ? lane : 0;
    int  i0 = items[(size_t)b * L + c0];
    bool v0 = (lane < L) && read_mask(mask, mmode, (size_t)b * L + c0);
    int  i1 = i0;
    bool v1 = false;
    if (64 + lane < L) {
        i1 = items[(size_t)b * L + 64 + lane];
        v1 = read_mask(mask, mmode, (size_t)b * L + 64 + lane);
    }
    const int len = __popcll(__ballot(v0)) + __popcll(__ballot(v1));

    const int g = lane >> 4, m16 = lane & 15;

    // lane's 8-dim chunk of h_u
    float hu8[8];
    load8f<BF>(emb_u, (size_t)xu * D + m16 * 8, hu8);

    // id for this wave's pass q (4 items/pass, subgroup g owns item 32wv+4q+g)
    auto get_id = [&](int q) -> int {
        const int idx = 32 * wv + 4 * q + g;
        const int src = (idx < len) ? idx : 0;
        return (src < 64) ? __shfl(i0, src) : __shfl(i1, src - 64);
    };

    float esum = 0.f;
    float acc8[8];
    #pragma unroll
    for (int k = 0; k < 8; ++k) acc8[k] = 0.f;

    const bool active = (wv == 0) || (32 * wv < len);
    if (active) {
        if constexpr (BF) {
            const unsigned short* AW = (const unsigned short*)Aw;
            const unsigned short* EI = (const unsigned short*)emb_i;
            uint4 ab[8], vb[8];
            #pragma unroll
            for (int q = 0; q < 8; ++q) {          // burst: 16 loads in flight
                const int id = get_id(q);
                ab[q] = *(const uint4*)(AW + (size_t)id * D + m16 * 8);
                vb[q] = *(const uint4*)(EI + (size_t)id * D + m16 * 8);
            }
            #pragma unroll
            for (int q = 0; q < 8; ++q) {          // consume
                float af[8];
                unpack8(ab[q], af);
                float s = 0.f;
                #pragma unroll
                for (int k = 0; k < 8; ++k) s += hu8[k] * af[k];
                s += __shfl_xor(s, 1); s += __shfl_xor(s, 2);
                s += __shfl_xor(s, 4); s += __shfl_xor(s, 8);
                const int idx = 32 * wv + 4 * q + g;
                const float e = (idx < len) ? __expf(s) : 0.f;
                esum += e;
                float vf[8];
                unpack8(vb[q], vf);
                #pragma unroll
                for (int k = 0; k < 8; ++k) acc8[k] += e * vf[k];
            }
        } else {
            float a0[8], u0[8], a1[8], u1[8];
            auto fetchf = [&](int q, float* a, float* v) {
                const int id = get_id(q);
                load8f<false>(Aw,    (size_t)id * D + m16 * 8, a);
                load8f<false>(emb_i, (size_t)id * D + m16 * 8, v);
            };
            fetchf(0, a0, u0);
            fetchf(1, a1, u1);
            for (int q = 0; q < 8; ++q) {
                float ca[8], cv[8];
                #pragma unroll
                for (int k = 0; k < 8; ++k) { ca[k] = a0[k]; cv[k] = u0[k]; }
                #pragma unroll
                for (int k = 0; k < 8; ++k) { a0[k] = a1[k]; u0[k] = u1[k]; }
                if (q + 2 < 8) fetchf(q + 2, a1, u1);
                float s = 0.f;
                #pragma unroll
                for (int k = 0; k < 8; ++k) s += hu8[k] * ca[k];
                s += __shfl_xor(s, 1); s += __shfl_xor(s, 2);
                s += __shfl_xor(s, 4); s += __shfl_xor(s, 8);
                const int idx = 32 * wv + 4 * q + g;
                const float e = (idx < len) ? __expf(s) : 0.f;
                esum += e;
                #pragma unroll
                for (int k = 0; k < 8; ++k) acc8[k] += e * cv[k];
            }
        }
        // combine the 4 subgroups within this wave
        esum += __shfl_xor(esum, 16);
        esum += __shfl_xor(esum, 32);
        #pragma unroll
        for (int k = 0; k < 8; ++k) {
            acc8[k] += __shfl_xor(acc8[k], 16);
            acc8[k] += __shfl_xor(acc8[k], 32);
        }
    }

    // ---- write wave partial to LDS (zeros if inactive) ----
    if (g == 0) {
        #pragma unroll
        for (int k = 0; k < 8; ++k) s_acc[wv][m16 * 8 + k] = acc8[k];
        if (m16 == 0) s_es[wv] = esum;
    }
    __syncthreads();

    // ---- wave 0 combines + writes row b ----
    if (wv == 0 && g == 0) {
        const float es = s_es[0] + s_es[1] + s_es[2] + s_es[3];
        float at[8];
        #pragma unroll
        for (int k = 0; k < 8; ++k)
            at[k] = s_acc[0][m16 * 8 + k] + s_acc[1][m16 * 8 + k]
                  + s_acc[2][m16 * 8 + k] + s_acc[3][m16 * 8 + k];
        const float inv = (es > 0.f) ? 1.f / es : 0.f;

        if constexpr (BF) {   // bit-exact pass-through of h_u
            uint4 raw = *(const uint4*)((const unsigned short*)emb_u
                                        + (size_t)xu * D + m16 * 8);
            *(uint4*)(h_out + (size_t)b * D2 + m16 * 8) = raw;
        } else {
            float r[8];
            load8f<false>(emb_u, (size_t)xu * D + m16 * 8, r);
            store8bf(h_out + (size_t)b * D2 + m16 * 8, r);
        }
        const int xb = x_b[b];
        float rb2[8], outv[8];
        load8f<BF>(emb_b, (size_t)xb * D + m16 * 8, rb2);
        #pragma unroll
        for (int k = 0; k < 8; ++k) outv[k] = rb2[k] + at[k] * inv;
        store8bf(h_out + (size_t)b * D2 + D + m16 * 8, outv);
    }
}

__global__ __launch_bounds__(256) void attn_kernel(
    const int* x_u, const int* x_b, const int* items, const void* mask,
    const void* emb_u, const void* emb_i, const void* emb_b, const void* A,
    unsigned short* h_out, int L)
{
    __shared__ float s_acc[4][128];
    __shared__ float s_es[4];

    const bool bf = probe_is_bf16((const unsigned int*)emb_u);
    const unsigned char* mb = (const unsigned char*)mask;
    const int mm = (mb[1] == 0) ? 0 : ((mb[0] == 1) ? 1 : 2);

    if (bf) attn_row<true >(x_u, x_b, items, mask, mm, emb_u, emb_i, emb_b, A, h_out, L, s_acc, s_es);
    else    attn_row<false>(x_u, x_b, items, mask, mm, emb_u, emb_i, emb_b, A, h_out, L, s_acc, s_es);
}

// ---------------------------------------------------------------------------
// Kernel 2 (v2): fused MLP.  512 threads (8 waves) per 16 rows -> 16 waves/CU
// resident (was 8), each wave computes 2 output-column tiles per stage.
// ---------------------------------------------------------------------------
template<bool BF>
__device__ __forceinline__ bf16x8 load_w8(const void* W, size_t off) {
    if constexpr (BF) {
        return *(const bf16x8*)((const unsigned short*)W + off);
    } else {
        const float* p = (const float*)W + off;
        float4 a = *(const float4*)p;
        float4 b = *(const float4*)(p + 4);
        bf16x8 r;
        r[0] = (short)f2bf(a.x); r[1] = (short)f2bf(a.y);
        r[2] = (short)f2bf(a.z); r[3] = (short)f2bf(a.w);
        r[4] = (short)f2bf(b.x); r[5] = (short)f2bf(b.y);
        r[6] = (short)f2bf(b.z); r[7] = (short)f2bf(b.w);
        return r;
    }
}

template<bool BF>
__device__ __forceinline__ void mlp_body(
    const unsigned short* __restrict__ X,
    const void* __restrict__ fc1_w, const void* __restrict__ fc1_b,
    const void* __restrict__ fc2_w, const void* __restrict__ fc2_b,
    const void* __restrict__ out_w, const void* __restrict__ out_b,
    void* __restrict__ out,
    unsigned short* h1_s, float (*po_s)[16])
{
    const int tid  = threadIdx.x;
    const int wave = tid >> 6;          // 0..7
    const int lane = tid & 63;
    const int l16  = lane & 15;
    const int quad = lane >> 4;
    const int mt   = blockIdx.x * 16;

    // ---- stage 1 ----
    bf16x8 afrag[8];
    const size_t abase = (size_t)(mt + l16) * D2 + quad * 8;
    #pragma unroll
    for (int kc = 0; kc < 8; ++kc)
        afrag[kc] = *(const bf16x8*)(X + abase + kc * 32);

    #pragma unroll
    for (int jj = 0; jj < 2; ++jj) {
        const int jt = wave * 2 + jj;
        const size_t bbase = (size_t)(jt * 16 + l16) * D2 + quad * 8;
        f32x4 acc = {0.f, 0.f, 0.f, 0.f};
        #pragma unroll
        for (int kc = 0; kc < 8; ++kc) {
            bf16x8 bfrag = load_w8<BF>(fc1_w, bbase + kc * 32);
            acc = __builtin_amdgcn_mfma_f32_16x16x32_bf16(afrag[kc], bfrag, acc, 0, 0, 0);
        }
        const int j  = jt * 16 + l16;
        const float bj = ld1<BF>(fc1_b, j);
        #pragma unroll
        for (int r = 0; r < 4; ++r) {
            float v = acc[r] + bj;
            v = v > 0.f ? v : 0.01f * v;
            h1_s[(quad * 4 + r) * H1P + j] = f2bf(v);
        }
    }
    __syncthreads();

    // ---- stage 2 + fused out-dot epilogue ----
    bf16x8 afrag2[8];
    #pragma unroll
    for (int kc = 0; kc < 8; ++kc)
        afrag2[kc] = *(const bf16x8*)&h1_s[l16 * H1P + quad * 8 + kc * 32];

    float po[4] = {0.f, 0.f, 0.f, 0.f};
    #pragma unroll
    for (int jj = 0; jj < 2; ++jj) {
        const int jt = wave * 2 + jj;
        const size_t bbase = (size_t)(jt * 16 + l16) * D2 + quad * 8;
        f32x4 acc = {0.f, 0.f, 0.f, 0.f};
        #pragma unroll
        for (int kc = 0; kc < 8; ++kc) {
            bf16x8 bfrag = load_w8<BF>(fc2_w, bbase + kc * 32);
            acc = __builtin_amdgcn_mfma_f32_16x16x32_bf16(afrag2[kc], bfrag, acc, 0, 0, 0);
        }
        const int j  = jt * 16 + l16;
        const float bj = ld1<BF>(fc2_b, j);
        const float wj = ld1<BF>(out_w, j);
        #pragma unroll
        for (int r = 0; r < 4; ++r) {
            float v = acc[r] + bj;
            v = v > 0.f ? v : 0.01f * v;
            po[r] += v * wj;
        }
    }
    #pragma unroll
    for (int r = 0; r < 4; ++r) {
        #pragma unroll
        for (int o = 1; o < 16; o <<= 1) po[r] += __shfl_xor(po[r], o);
    }
    if (l16 == 0) {
        #pragma unroll
        for (int r = 0; r < 4; ++r) po_s[wave][quad * 4 + r] = po[r];
    }
    __syncthreads();

    if (tid < 16) {
        float v = ld1<BF>(out_b, 0);
        #pragma unroll
        for (int w = 0; w < 8; ++w) v += po_s[w][tid];
        if constexpr (BF) ((unsigned short*)out)[mt + tid] = f2bf(v);
        else              ((float*)out)[mt + tid] = v;
    }
}

__global__ __launch_bounds__(512, 4) void mlp_kernel(
    const unsigned short* X,
    const void* fc1_w, const void* fc1_b, const void* fc2_w, const void* fc2_b,
    const void* out_w, const void* out_b, void* out, const void* probe)
{
    __shared__ unsigned short h1_s[16 * H1P];
    __shared__ float po_s[8][16];

    const bool bf = probe_is_bf16((const unsigned int*)probe);
    if (bf) mlp_body<true >(X, fc1_w, fc1_b, fc2_w, fc2_b, out_w, out_b, out, h1_s, po_s);
    else    mlp_body<false>(X, fc1_w, fc1_b, fc2_w, fc2_b, out_w, out_b, out, h1_s, po_s);
}

extern "C" void kernel_launch(void* const* d_in, const int* in_sizes, int n_in,
                              void* d_out, int out_size, void* d_ws, size_t ws_size,
                              hipStream_t stream) {
    const int*  x_u   = (const int*)d_in[0];
    const int*  x_b   = (const int*)d_in[1];
    const int*  items = (const int*)d_in[2];
    const void* mask  = d_in[3];
    const void* emb_u = d_in[4];
    const void* emb_i = d_in[5];
    const void* emb_b = d_in[6];
    const void* A     = d_in[7];
    const void* fc1_w = d_in[8];
    const void* fc1_b = d_in[9];
    const void* fc2_w = d_in[10];
    const void* fc2_b = d_in[11];
    const void* out_w = d_in[12];
    const void* out_b = d_in[13];

    const int B = in_sizes[0];
    const int L = in_sizes[2] / B;

    // ws: h [B,256] bf16 (4MB)
    unsigned short* h = (unsigned short*)d_ws;

    attn_kernel<<<B, 256, 0, stream>>>(x_u, x_b, items, mask,
                                       emb_u, emb_i, emb_b, A, h, L);
    mlp_kernel<<<B / 16, 512, 0, stream>>>(h, fc1_w, fc1_b, fc2_w, fc2_b,
                                           out_w, out_b, d_out, emb_i);
}

// Round 4
// 299.872 us; speedup vs baseline: 1.0225x; 1.0225x over previous
//
#include <hip/hip_runtime.h>
#include <hip/hip_bf16.h>

#define D   128   // EMBED_DIM
#define D2  256   // 2*EMBED_DIM
#define XS  264   // padded X tile row (ushorts): 132 dwords % 32 = 4 -> 2-way free
#define H1P 272   // padded h1 tile row (ushorts)

typedef short bf16x8 __attribute__((ext_vector_type(8)));
typedef float f32x4  __attribute__((ext_vector_type(4)));

__device__ __forceinline__ float bf2f(unsigned short u) {
    return __uint_as_float(((unsigned int)u) << 16);
}
__device__ __forceinline__ float bflo(unsigned int p) { return __uint_as_float(p << 16); }
__device__ __forceinline__ float bfhi(unsigned int p) { return __uint_as_float(p & 0xffff0000u); }
__device__ __forceinline__ unsigned short f2bf(float f) {
    __hip_bfloat16 h = __float2bfloat16(f);
    return *(unsigned short*)&h;
}

template<bool BF>
__device__ __forceinline__ float ld1(const void* p, size_t i) {
    if constexpr (BF) return bf2f(((const unsigned short*)p)[i]);
    else              return ((const float*)p)[i];
}

template<bool BF>
__device__ __forceinline__ void load8f(const void* p, size_t elem_off, float* r) {
    if constexpr (BF) {
        uint4 v = *(const uint4*)((const unsigned short*)p + elem_off);
        r[0]=bflo(v.x); r[1]=bfhi(v.x); r[2]=bflo(v.y); r[3]=bfhi(v.y);
        r[4]=bflo(v.z); r[5]=bfhi(v.z); r[6]=bflo(v.w); r[7]=bfhi(v.w);
    } else {
        const float4* q = (const float4*)((const float*)p + elem_off);
        float4 a = q[0], b = q[1];
        r[0]=a.x; r[1]=a.y; r[2]=a.z; r[3]=a.w;
        r[4]=b.x; r[5]=b.y; r[6]=b.z; r[7]=b.w;
    }
}

__device__ __forceinline__ void unpack8(uint4 v, float* r) {
    r[0]=bflo(v.x); r[1]=bfhi(v.x); r[2]=bflo(v.y); r[3]=bfhi(v.y);
    r[4]=bflo(v.z); r[5]=bfhi(v.z); r[6]=bflo(v.w); r[7]=bfhi(v.w);
}

__device__ __forceinline__ void store8bf(unsigned short* p, const float* r) {
    union { unsigned short u[8]; uint4 v; } pk;
    #pragma unroll
    for (int k = 0; k < 8; ++k) pk.u[k] = f2bf(r[k]);
    *(uint4*)p = pk.v;
}

__device__ __forceinline__ bool read_mask(const void* mask, int mmode, size_t i) {
    if (mmode == 0) return ((const int*)mask)[i] != 0;
    if (mmode == 1) return ((const unsigned char*)mask)[i] != 0;
    return ((const unsigned short*)mask)[i] != 0;
}

// Wave-local dtype probe (no LDS, no barrier): identical count in every wave.
__device__ __forceinline__ bool probe_is_bf16(const unsigned int* probe) {
    const int lane = threadIdx.x & 63;
    int cnt = 0;
    #pragma unroll
    for (int i = 0; i < 4; ++i) {
        unsigned int e = (probe[lane + 64 * i] >> 7) & 0xffu;
        cnt += (e >= 90 && e < 130) ? 1 : 0;
    }
    #pragma unroll
    for (int o = 32; o; o >>= 1) cnt += __shfl_xor(cnt, o);
    return cnt >= 128;
}

// ---------------------------------------------------------------------------
// Attention for ONE row by ONE wave (the R1-verified v1 body), writing the
// row's [h_u | h_b + h_x] into an LDS X-tile row instead of global.
// ---------------------------------------------------------------------------
template<bool BF>
__device__ __forceinline__ void attn_one_row(
    const int* __restrict__ x_u, const int* __restrict__ x_b,
    const int* __restrict__ items, const void* __restrict__ mask, int mmode,
    const void* __restrict__ emb_u, const void* __restrict__ emb_i,
    const void* __restrict__ emb_b, const void* __restrict__ Aw,
    unsigned short* __restrict__ x_row, int b, int L)
{
    const int lane = threadIdx.x & 63;
    const int xu = x_u[b];

    // ---- items + mask: lane holds item[lane] (i0), item[64+lane] (i1) ----
    const int  c0 = (lane < L) ? lane : 0;
    int  i0 = items[(size_t)b * L + c0];
    bool v0 = (lane < L) && read_mask(mask, mmode, (size_t)b * L + c0);
    int  i1 = i0;
    bool v1 = false;
    if (64 + lane < L) {
        i1 = items[(size_t)b * L + 64 + lane];
        v1 = read_mask(mask, mmode, (size_t)b * L + 64 + lane);
    }
    const int len = __popcll(__ballot(v0)) + __popcll(__ballot(v1));

    const int g = lane >> 4, m16 = lane & 15;

    // lane's 8-dim chunk of h_u
    float hu8[8];
    load8f<BF>(emb_u, (size_t)xu * D + m16 * 8, hu8);

    // id for pass p (4 items/pass, subgroup g owns item 4p+g); pads -> item 0
    auto get_id = [&](int p) -> int {
        const int idx = 4 * p + g;
        const int src = (idx < len) ? idx : 0;
        return (src < 64) ? __shfl(i0, src) : __shfl(i1, src - 64);
    };

    float esum = 0.f;
    float acc8[8];
    #pragma unroll
    for (int k = 0; k < 8; ++k) acc8[k] = 0.f;

    if constexpr (BF) {
        const unsigned short* AW = (const unsigned short*)Aw;
        const unsigned short* EI = (const unsigned short*)emb_i;
        // 4 groups x 8 passes covers len <= 128
        for (int grp = 0; grp < 4; ++grp) {
            if (grp == 0 || grp * 32 < len) {          // wave-uniform skip
                uint4 ab[8], vb[8];
                #pragma unroll
                for (int q = 0; q < 8; ++q) {          // burst: 16 loads in flight
                    const int id = get_id(grp * 8 + q);
                    ab[q] = *(const uint4*)(AW + (size_t)id * D + m16 * 8);
                    vb[q] = *(const uint4*)(EI + (size_t)id * D + m16 * 8);
                }
                #pragma unroll
                for (int q = 0; q < 8; ++q) {          // consume
                    float af[8];
                    unpack8(ab[q], af);
                    float s = 0.f;
                    #pragma unroll
                    for (int k = 0; k < 8; ++k) s += hu8[k] * af[k];
                    s += __shfl_xor(s, 1); s += __shfl_xor(s, 2);
                    s += __shfl_xor(s, 4); s += __shfl_xor(s, 8);
                    const int idx = 4 * (grp * 8 + q) + g;
                    const float e = (idx < len) ? __expf(s) : 0.f;
                    esum += e;
                    float vf[8];
                    unpack8(vb[q], vf);
                    #pragma unroll
                    for (int k = 0; k < 8; ++k) acc8[k] += e * vf[k];
                }
            }
        }
    } else {
        const int NP = (len + 3) >> 2;
        auto fetchf = [&](int p, float* a, float* v) {
            const int id = get_id(p);
            load8f<false>(Aw,    (size_t)id * D + m16 * 8, a);
            load8f<false>(emb_i, (size_t)id * D + m16 * 8, v);
        };
        float a0[8], u0[8], a1[8], u1[8];
        fetchf(0, a0, u0);
        if (1 < NP) fetchf(1, a1, u1);
        for (int p = 0; p < NP; ++p) {
            float ca[8], cv[8];
            #pragma unroll
            for (int k = 0; k < 8; ++k) { ca[k] = a0[k]; cv[k] = u0[k]; }
            #pragma unroll
            for (int k = 0; k < 8; ++k) { a0[k] = a1[k]; u0[k] = u1[k]; }
            if (p + 2 < NP) fetchf(p + 2, a1, u1);
            float s = 0.f;
            #pragma unroll
            for (int k = 0; k < 8; ++k) s += hu8[k] * ca[k];
            s += __shfl_xor(s, 1); s += __shfl_xor(s, 2);
            s += __shfl_xor(s, 4); s += __shfl_xor(s, 8);
            const int idx = 4 * p + g;
            const float e = (idx < len) ? __expf(s) : 0.f;
            esum += e;
            #pragma unroll
            for (int k = 0; k < 8; ++k) acc8[k] += e * cv[k];
        }
    }

    // combine the 4 item-subgroups
    esum += __shfl_xor(esum, 16);
    esum += __shfl_xor(esum, 32);
    #pragma unroll
    for (int k = 0; k < 8; ++k) {
        acc8[k] += __shfl_xor(acc8[k], 16);
        acc8[k] += __shfl_xor(acc8[k], 32);
    }
    const float inv = (esum > 0.f) ? 1.f / esum : 0.f;

    // ---- write X-tile row: lanes 0..15, 8 dims each, both halves ----
    if (g == 0) {
        if constexpr (BF) {   // bit-exact pass-through of h_u
            uint4 raw = *(const uint4*)((const unsigned short*)emb_u
                                        + (size_t)xu * D + m16 * 8);
            *(uint4*)(x_row + m16 * 8) = raw;
        } else {
            float r[8];
            load8f<false>(emb_u, (size_t)xu * D + m16 * 8, r);
            store8bf(x_row + m16 * 8, r);
        }
        const int xb = x_b[b];
        float rb2[8], outv[8];
        load8f<BF>(emb_b, (size_t)xb * D + m16 * 8, rb2);
        #pragma unroll
        for (int k = 0; k < 8; ++k) outv[k] = rb2[k] + acc8[k] * inv;
        store8bf(x_row + D + m16 * 8, outv);
    }
}

// ---------------------------------------------------------------------------
// Fused kernel: ONE BLOCK (8 waves, 512 thr) per 16 rows.
// Phase 1: wave w runs attention for rows w and w+8 -> X tile in LDS.
// Phase 2: barrier, then MFMA MLP (fc1 -> h1_s -> fc2 -> fused out-dot).
// ---------------------------------------------------------------------------
template<bool BF>
__device__ __forceinline__ bf16x8 load_w8(const void* W, size_t off) {
    if constexpr (BF) {
        return *(const bf16x8*)((const unsigned short*)W + off);
    } else {
        const float* p = (const float*)W + off;
        float4 a = *(const float4*)p;
        float4 b = *(const float4*)(p + 4);
        bf16x8 r;
        r[0] = (short)f2bf(a.x); r[1] = (short)f2bf(a.y);
        r[2] = (short)f2bf(a.z); r[3] = (short)f2bf(a.w);
        r[4] = (short)f2bf(b.x); r[5] = (short)f2bf(b.y);
        r[6] = (short)f2bf(b.z); r[7] = (short)f2bf(b.w);
        return r;
    }
}

template<bool BF>
__device__ __forceinline__ void fused_body(
    const int* __restrict__ x_u, const int* __restrict__ x_b,
    const int* __restrict__ items, const void* __restrict__ mask, int mmode,
    const void* __restrict__ emb_u, const void* __restrict__ emb_i,
    const void* __restrict__ emb_b, const void* __restrict__ Aw,
    const void* __restrict__ fc1_w, const void* __restrict__ fc1_b,
    const void* __restrict__ fc2_w, const void* __restrict__ fc2_b,
    const void* __restrict__ out_w, const void* __restrict__ out_b,
    void* __restrict__ out, int L,
    unsigned short* x_s, unsigned short* h1_s, float (*po_s)[16])
{
    const int tid  = threadIdx.x;
    const int wave = tid >> 6;          // 0..7
    const int lane = tid & 63;
    const int l16  = lane & 15;
    const int quad = lane >> 4;
    const int mt   = blockIdx.x * 16;

    // ---- Phase 1: attention, 2 rows per wave ----
    #pragma unroll
    for (int rr = 0; rr < 2; ++rr) {
        const int r = wave + rr * 8;
        attn_one_row<BF>(x_u, x_b, items, mask, mmode, emb_u, emb_i, emb_b, Aw,
                         &x_s[r * XS], mt + r, L);
    }
    __syncthreads();

    // ---- Phase 2, stage 1: X @ fc1_w^T ----
    bf16x8 afrag[8];
    #pragma unroll
    for (int kc = 0; kc < 8; ++kc)
        afrag[kc] = *(const bf16x8*)&x_s[l16 * XS + quad * 8 + kc * 32];

    #pragma unroll
    for (int jj = 0; jj < 2; ++jj) {
        const int jt = wave * 2 + jj;
        const size_t bbase = (size_t)(jt * 16 + l16) * D2 + quad * 8;
        f32x4 acc = {0.f, 0.f, 0.f, 0.f};
        #pragma unroll
        for (int kc = 0; kc < 8; ++kc) {
            bf16x8 bfrag = load_w8<BF>(fc1_w, bbase + kc * 32);
            acc = __builtin_amdgcn_mfma_f32_16x16x32_bf16(afrag[kc], bfrag, acc, 0, 0, 0);
        }
        const int j  = jt * 16 + l16;
        const float bj = ld1<BF>(fc1_b, j);
        #pragma unroll
        for (int r = 0; r < 4; ++r) {
            float v = acc[r] + bj;
            v = v > 0.f ? v : 0.01f * v;
            h1_s[(quad * 4 + r) * H1P + j] = f2bf(v);
        }
    }
    __syncthreads();

    // ---- stage 2 + fused out-dot epilogue ----
    bf16x8 afrag2[8];
    #pragma unroll
    for (int kc = 0; kc < 8; ++kc)
        afrag2[kc] = *(const bf16x8*)&h1_s[l16 * H1P + quad * 8 + kc * 32];

    float po[4] = {0.f, 0.f, 0.f, 0.f};
    #pragma unroll
    for (int jj = 0; jj < 2; ++jj) {
        const int jt = wave * 2 + jj;
        const size_t bbase = (size_t)(jt * 16 + l16) * D2 + quad * 8;
        f32x4 acc = {0.f, 0.f, 0.f, 0.f};
        #pragma unroll
        for (int kc = 0; kc < 8; ++kc) {
            bf16x8 bfrag = load_w8<BF>(fc2_w, bbase + kc * 32);
            acc = __builtin_amdgcn_mfma_f32_16x16x32_bf16(afrag2[kc], bfrag, acc, 0, 0, 0);
        }
        const int j  = jt * 16 + l16;
        const float bj = ld1<BF>(fc2_b, j);
        const float wj = ld1<BF>(out_w, j);
        #pragma unroll
        for (int r = 0; r < 4; ++r) {
            float v = acc[r] + bj;
            v = v > 0.f ? v : 0.01f * v;
            po[r] += v * wj;
        }
    }
    #pragma unroll
    for (int r = 0; r < 4; ++r) {
        #pragma unroll
        for (int o = 1; o < 16; o <<= 1) po[r] += __shfl_xor(po[r], o);
    }
    if (l16 == 0) {
        #pragma unroll
        for (int r = 0; r < 4; ++r) po_s[wave][quad * 4 + r] = po[r];
    }
    __syncthreads();

    if (tid < 16) {
        float v = ld1<BF>(out_b, 0);
        #pragma unroll
        for (int w = 0; w < 8; ++w) v += po_s[w][tid];
        if constexpr (BF) ((unsigned short*)out)[mt + tid] = f2bf(v);
        else              ((float*)out)[mt + tid] = v;
    }
}

__global__ __launch_bounds__(512, 4) void fused_kernel(
    const int* x_u, const int* x_b, const int* items, const void* mask,
    const void* emb_u, const void* emb_i, const void* emb_b, const void* A,
    const void* fc1_w, const void* fc1_b, const void* fc2_w, const void* fc2_b,
    const void* out_w, const void* out_b, void* out, int L)
{
    __shared__ unsigned short x_s[16 * XS];
    __shared__ unsigned short h1_s[16 * H1P];
    __shared__ float po_s[8][16];

    const bool bf = probe_is_bf16((const unsigned int*)emb_u);
    const unsigned char* mb = (const unsigned char*)mask;
    const int mm = (mb[1] == 0) ? 0 : ((mb[0] == 1) ? 1 : 2);

    if (bf) fused_body<true >(x_u, x_b, items, mask, mm, emb_u, emb_i, emb_b, A,
                              fc1_w, fc1_b, fc2_w, fc2_b, out_w, out_b, out, L,
                              x_s, h1_s, po_s);
    else    fused_body<false>(x_u, x_b, items, mask, mm, emb_u, emb_i, emb_b, A,
                              fc1_w, fc1_b, fc2_w, fc2_b, out_w, out_b, out, L,
                              x_s, h1_s, po_s);
}

extern "C" void kernel_launch(void* const* d_in, const int* in_sizes, int n_in,
                              void* d_out, int out_size, void* d_ws, size_t ws_size,
                              hipStream_t stream) {
    const int*  x_u   = (const int*)d_in[0];
    const int*  x_b   = (const int*)d_in[1];
    const int*  items = (const int*)d_in[2];
    const void* mask  = d_in[3];
    const void* emb_u = d_in[4];
    const void* emb_i = d_in[5];
    const void* emb_b = d_in[6];
    const void* A     = d_in[7];
    const void* fc1_w = d_in[8];
    const void* fc1_b = d_in[9];
    const void* fc2_w = d_in[10];
    const void* fc2_b = d_in[11];
    const void* out_w = d_in[12];
    const void* out_b = d_in[13];

    const int B = in_sizes[0];
    const int L = in_sizes[2] / B;

    fused_kernel<<<B / 16, 512, 0, stream>>>(x_u, x_b, items, mask,
                                             emb_u, emb_i, emb_b, A,
                                             fc1_w, fc1_b, fc2_w, fc2_b,
                                             out_w, out_b, d_out, L);
}